// Round 18
// baseline (687.115 us; speedup 1.0000x reference)
//
#include <hip/hip_runtime.h>
#include <hip/hip_bf16.h>

#define HW 65536
#define WIDTH 256
#define SP_OFF 77856768ull   // ws offset of spatial-out blob (67,108,864 B bf16)

typedef __attribute__((ext_vector_type(8))) short short8v;
typedef __attribute__((ext_vector_type(4))) short short4v;
typedef __attribute__((ext_vector_type(4))) float f32x4;

__device__ inline float bf2f(unsigned short u) {
  unsigned int i = ((unsigned int)u) << 16;
  float f; __builtin_memcpy(&f, &i, 4); return f;
}
__device__ inline unsigned short f2bf(float x) {
  __hip_bfloat16 h = __float2bfloat16(x);
  unsigned short u; __builtin_memcpy(&u, &h, 2); return u;
}

// swizzled LDS indexers for chan body (granule = 8 bf16 = 16B)
#define XH_IDX(p, g) ((p)*64 + ((((g) ^ ((p)&7)))<<3))
#define QC_IDX(ch, px) ((ch)*256 + ((((px)>>3) ^ ((ch)&7))<<3) + ((px)&7))
#define QCG_IDX(ch, G) ((ch)*256 + ((((G) ^ ((ch)&7)))<<3))

// ================= spatial body: 8 windows per block (setup amortized) =================
// LDS map: shbuf 0..18432 | ks ..27648 | vs ..36864 | vsT ..46080 (rs_tok aliases
// first 256B of vsT; disjoint lifetimes) | biasx ..80896 ([4][64][68] bf16)
__device__ __forceinline__ void spatial_body(
    unsigned char* smem, int b, int grp,
    const float* __restrict__ x, const float* __restrict__ illu,
    const float* __restrict__ ln1w, const float* __restrict__ wqkv,
    const float* __restrict__ bqkv, const float* __restrict__ rpb,
    const float* __restrict__ wproj, const float* __restrict__ bproj,
    float* __restrict__ out, unsigned short* __restrict__ sp, int use_sp)
{
  unsigned short* shbuf = (unsigned short*)smem;            // 9216 shorts
  unsigned short* ks    = (unsigned short*)(smem + 18432);
  unsigned short* vs    = (unsigned short*)(smem + 27648);
  unsigned short* vsT   = (unsigned short*)(smem + 36864);
  float* rs_tok         = (float*)(smem + 36864);           // aliases vsT prefix
  unsigned short* biasx = (unsigned short*)(smem + 46080);  // [4][64][68] bf16

  unsigned short* xw = shbuf;
  unsigned short* qs = shbuf + 4608;

  const int tid = threadIdx.x;
  const float* xb = x + (size_t)b * 64 * HW;
  const float* ib = illu + (size_t)b * 64 * HW;

  const int lane = tid & 63;
  const int w = tid >> 6;
  const int fr = lane & 15;
  const int fg = lane >> 4;
  const int hb = w * 16;

  // expand relative-position bias once per block: biasx[w][q][k]
  for (int i = tid; i < 16384; i += 256) {
    int w4 = i >> 12, q = (i >> 6) & 63, k = i & 63;
    int ridx = ((q >> 3) - (k >> 3) + 7) * 15 + ((q & 7) - (k & 7) + 7);
    biasx[(w4 * 64 + q) * 68 + k] = f2bf(rpb[ridx * 4 + w4]);
  }

  short8v bfq[3][2];
  float biasr[3];
  #pragma unroll
  for (int part = 0; part < 3; ++part) {
    int o = part * 64 + hb + fr;
    biasr[part] = bqkv[o];
    #pragma unroll
    for (int kh = 0; kh < 2; ++kh)
      #pragma unroll
      for (int j = 0; j < 8; ++j) {
        int c = kh * 32 + fg * 8 + j;
        bfq[part][kh][j] = (short)f2bf(wqkv[c * 192 + o] * ln1w[c]);
      }
  }
  short8v bfp[2];
  #pragma unroll
  for (int kh = 0; kh < 2; ++kh)
    #pragma unroll
    for (int j = 0; j < 8; ++j) {
      int c = kh * 32 + fg * 8 + j;
      bfp[kh][j] = (short)f2bf(wproj[c * 64 + hb + fr]);
    }

  for (int wi = 0; wi < 8; ++wi) {
    const int win = (grp << 3) + wi;
    const int h0 = (win >> 5) << 3;
    const int w0 = (win & 31) << 3;

    for (int i = tid; i < 1024; i += 256) {
      int c = i >> 4, seg = i & 15;
      int row = seg >> 1, half = (seg & 1) * 4;
      float4 v4 = *(const float4*)&xb[(size_t)c * HW + (h0 + row) * WIDTH + w0 + half];
      int p = row * 8 + half;
      xw[(p+0)*72 + c] = f2bf(v4.x);
      xw[(p+1)*72 + c] = f2bf(v4.y);
      xw[(p+2)*72 + c] = f2bf(v4.z);
      xw[(p+3)*72 + c] = f2bf(v4.w);
    }
    __syncthreads();
    {
      int l = tid >> 2, q4 = tid & 3;
      short8v v8a = *(const short8v*)&xw[l*72 + q4*16];
      short8v v8b = *(const short8v*)&xw[l*72 + q4*16 + 8];
      float s = 0.f, s2 = 0.f;
      #pragma unroll
      for (int j = 0; j < 8; ++j) {
        float va = bf2f((unsigned short)v8a[j]), vb = bf2f((unsigned short)v8b[j]);
        s += va + vb; s2 += va * va + vb * vb;
      }
      s += __shfl_down(s, 1); s2 += __shfl_down(s2, 1);
      s += __shfl_down(s, 2); s2 += __shfl_down(s2, 2);
      if (q4 == 0) {
        float mean = s * 0.015625f;
        float var = s2 * 0.015625f - mean * mean;
        rs_tok[l] = rsqrtf(var + 1e-5f);
      }
    }
    __syncthreads();
    // qkv via MFMA (B-frags in registers)
    {
      short8v a[4][2];
      #pragma unroll
      for (int rt = 0; rt < 4; ++rt)
        #pragma unroll
        for (int kh = 0; kh < 2; ++kh)
          a[rt][kh] = *(const short8v*)&xw[(rt*16 + fr)*72 + kh*32 + fg*8];
      #pragma unroll
      for (int part = 0; part < 3; ++part) {
        float bias = biasr[part];
        #pragma unroll
        for (int rt = 0; rt < 4; ++rt) {
          f32x4 acc = {0.f, 0.f, 0.f, 0.f};
          acc = __builtin_amdgcn_mfma_f32_16x16x32_bf16(a[rt][0], bfq[part][0], acc, 0, 0, 0);
          acc = __builtin_amdgcn_mfma_f32_16x16x32_bf16(a[rt][1], bfq[part][1], acc, 0, 0, 0);
          #pragma unroll
          for (int r = 0; r < 4; ++r) {
            int t = rt*16 + fg*4 + r;
            float val = acc[r] * rs_tok[t] + bias;
            if (part == 0)      qs[t*72 + hb + fr] = f2bf(val * 0.25f);
            else if (part == 1) ks[t*72 + hb + fr] = f2bf(val);
            else                vs[t*72 + hb + fr] = f2bf(val);
          }
        }
      }
    }
    __syncthreads();
    // stage illu -> xw
    for (int i = tid; i < 1024; i += 256) {
      int c = i >> 4, seg = i & 15;
      int row = seg >> 1, half = (seg & 1) * 4;
      float4 v4 = *(const float4*)&ib[(size_t)c * HW + (h0 + row) * WIDTH + w0 + half];
      int p = row * 8 + half;
      xw[(p+0)*72 + c] = f2bf(v4.x);
      xw[(p+1)*72 + c] = f2bf(v4.y);
      xw[(p+2)*72 + c] = f2bf(v4.z);
      xw[(p+3)*72 + c] = f2bf(v4.w);
    }
    __syncthreads();
    // modulate V, build swizzled V^T (vsT prefix overwrites rs_tok alias: dead now)
    for (int i = tid; i < 4096; i += 256) {
      int l = i >> 6, c = i & 63;
      unsigned short vb16 = f2bf(bf2f(vs[l*72 + c]) * bf2f(xw[l*72 + c]));
      vs[l*72 + c] = vb16;
      vsT[c*72 + ((((l >> 3) ^ (c & 7)) << 3) | (l & 7))] = vb16;
    }
    __syncthreads();
    // attention: S^T = mfma(K,Q), softmax in regs, PV via P-buffers in shbuf
    float inv_s[4];
    {
      short8v zero8 = {0,0,0,0,0,0,0,0};
      short8v kf[4], qf[4];
      #pragma unroll
      for (int t = 0; t < 4; ++t) {
        if (fg < 2) {
          kf[t] = *(const short8v*)&ks[(t*16 + fr)*72 + hb + fg*8];
          qf[t] = *(const short8v*)&qs[(t*16 + fr)*72 + hb + fg*8];
        } else { kf[t] = zero8; qf[t] = zero8; }
      }
      f32x4 st[4][4];
      #pragma unroll
      for (int kt = 0; kt < 4; ++kt)
        #pragma unroll
        for (int qt = 0; qt < 4; ++qt) {
          f32x4 z = {0.f, 0.f, 0.f, 0.f};
          st[kt][qt] = __builtin_amdgcn_mfma_f32_16x16x32_bf16(kf[kt], qf[qt], z, 0, 0, 0);
        }
      float sc[4][16];
      #pragma unroll
      for (int qt = 0; qt < 4; ++qt) {
        const unsigned short* brow = &biasx[(w * 64 + qt * 16 + fr) * 68];
        float mx = -1e30f;
        #pragma unroll
        for (int kt = 0; kt < 4; ++kt) {
          short4v b4 = *(const short4v*)&brow[kt * 16 + fg * 4];
          #pragma unroll
          for (int r = 0; r < 4; ++r) {
            float v = st[kt][qt][r] + bf2f((unsigned short)b4[r]);
            sc[qt][kt*4 + r] = v;
            mx = fmaxf(mx, v);
          }
        }
        mx = fmaxf(mx, __shfl_xor(mx, 16));
        mx = fmaxf(mx, __shfl_xor(mx, 32));
        float ss = 0.f;
        #pragma unroll
        for (int j = 0; j < 16; ++j) { float e = __expf(sc[qt][j] - mx); sc[qt][j] = e; ss += e; }
        ss += __shfl_xor(ss, 16);
        ss += __shfl_xor(ss, 32);
        inv_s[qt] = 1.f / ss;
      }
      __syncthreads();
      unsigned short* pb = shbuf + w * 2304;
      f32x4 ot[4];
      #pragma unroll
      for (int nt = 0; nt < 4; ++nt) { f32x4 z = {0.f,0.f,0.f,0.f}; ot[nt] = z; }
      #pragma unroll
      for (int P = 0; P < 2; ++P) {
        #pragma unroll
        for (int qt = 0; qt < 4; ++qt)
          #pragma unroll
          for (int k2 = 0; k2 < 2; ++k2) {
            int kt = 2*P + k2;
            unsigned int lo = (unsigned)f2bf(sc[qt][kt*4+0]) | ((unsigned)f2bf(sc[qt][kt*4+1]) << 16);
            unsigned int hi = (unsigned)f2bf(sc[qt][kt*4+2]) | ((unsigned)f2bf(sc[qt][kt*4+3]) << 16);
            uint2 pk; pk.x = lo; pk.y = hi;
            *(uint2*)&pb[(qt*16 + fr)*36 + k2*16 + fg*4] = pk;
          }
        __syncthreads();
        short8v av = *(const short8v*)&vsT[(hb + fr)*72 + (((P*4 + fg) ^ ((hb + fr) & 7)) << 3)];
        #pragma unroll
        for (int nt = 0; nt < 4; ++nt) {
          short4v p0 = *(const short4v*)&pb[(nt*16 + fr)*36 + fg*8];
          short4v p1 = *(const short4v*)&pb[(nt*16 + fr)*36 + fg*8 + 4];
          short8v bv;
          #pragma unroll
          for (int j = 0; j < 4; ++j) { bv[j] = p0[j]; bv[4+j] = p1[j]; }
          ot[nt] = __builtin_amdgcn_mfma_f32_16x16x32_bf16(av, bv, ot[nt], 0, 0, 0);
        }
        __syncthreads();
      }
      #pragma unroll
      for (int nt = 0; nt < 4; ++nt) {
        float iv = inv_s[nt];
        unsigned int lo = (unsigned)f2bf(ot[nt][0]*iv) | ((unsigned)f2bf(ot[nt][1]*iv) << 16);
        unsigned int hi = (unsigned)f2bf(ot[nt][2]*iv) | ((unsigned)f2bf(ot[nt][3]*iv) << 16);
        uint2 pk; pk.x = lo; pk.y = hi;
        *(uint2*)&ks[(nt*16 + fr)*72 + hb + fg*4] = pk;
      }
    }
    __syncthreads();
    // proj (B-frag in registers); result -> vs
    {
      short8v a[4][2];
      #pragma unroll
      for (int rt = 0; rt < 4; ++rt)
        #pragma unroll
        for (int kh = 0; kh < 2; ++kh)
          a[rt][kh] = *(const short8v*)&ks[(rt*16 + fr)*72 + kh*32 + fg*8];
      #pragma unroll
      for (int rt = 0; rt < 4; ++rt) {
        f32x4 acc = {0.f, 0.f, 0.f, 0.f};
        acc = __builtin_amdgcn_mfma_f32_16x16x32_bf16(a[rt][0], bfp[0], acc, 0, 0, 0);
        acc = __builtin_amdgcn_mfma_f32_16x16x32_bf16(a[rt][1], bfp[1], acc, 0, 0, 0);
        #pragma unroll
        for (int r = 0; r < 4; ++r)
          vs[(rt*16 + fg*4 + r)*72 + hb + fr] = f2bf(acc[r]);
      }
    }
    __syncthreads();
    if (use_sp) {
      unsigned short* spw = sp + (size_t)(b * 1024 + win) * 4096;
      for (int i = tid; i < 1024; i += 256) {
        int row = i >> 7, rem = i & 127;
        int c = rem >> 1, half = (rem & 1) * 4;
        int p = row * 8 + half;
        size_t gofs = (size_t)c * HW + (h0 + row) * WIDTH + w0 + half;
        float4 xr4 = *(const float4*)&xb[gofs];
        float bp = bproj[c];
        unsigned int lo = (unsigned)f2bf(xr4.x + bp + bf2f(vs[(p+0)*72 + c]))
                        | ((unsigned)f2bf(xr4.y + bp + bf2f(vs[(p+1)*72 + c])) << 16);
        unsigned int hi = (unsigned)f2bf(xr4.z + bp + bf2f(vs[(p+2)*72 + c]))
                        | ((unsigned)f2bf(xr4.w + bp + bf2f(vs[(p+3)*72 + c])) << 16);
        uint2 pk; pk.x = lo; pk.y = hi;
        *(uint2*)&spw[row*512 + c*8 + half] = pk;
      }
    } else {
      for (int i = tid; i < 1024; i += 256) {
        int o = i >> 4, seg = i & 15;
        int row = seg >> 1, half = (seg & 1) * 4;
        int p = row * 8 + half;
        size_t gofs = (size_t)o * HW + (h0 + row) * WIDTH + w0 + half;
        float4 xr4 = *(const float4*)&xb[gofs];
        float bp = bproj[o];
        float4 r;
        r.x = xr4.x + bp + bf2f(vs[(p+0)*72 + o]);
        r.y = xr4.y + bp + bf2f(vs[(p+1)*72 + o]);
        r.z = xr4.z + bp + bf2f(vs[(p+2)*72 + o]);
        r.w = xr4.w + bp + bf2f(vs[(p+3)*72 + o]);
        *(float4*)&out[(size_t)b * 64 * HW + gofs] = r;
      }
    }
    __syncthreads();
  }
}

// ================= channel body (round-9 structure; b = XCD, tile sequential) =================
__device__ __forceinline__ void chan_body(
    unsigned char* smem, int b, int tile,
    const float* __restrict__ x, const float* __restrict__ illu,
    const float* __restrict__ ln2w, const float* __restrict__ w1,
    const float* __restrict__ wdw,
    unsigned short* __restrict__ vm, float* __restrict__ Gp,
    float* __restrict__ Nqp, float* __restrict__ Nkp)
{
  unsigned short* xh = (unsigned short*)smem;             // 324*64 shorts (41472B)
  unsigned short* tb = (unsigned short*)(smem + 41472);   // 32*360 shorts (23040B)
  unsigned short* qc = (unsigned short*)(smem + 64512);   // 16*256 shorts
  unsigned short* kc = (unsigned short*)(smem + 72704);   // 16*256 shorts
  float* rsp = (float*)tb;   // scratch alias, dead before tb's first gemm write

  const int tid = threadIdx.x;
  const int blk = (b << 8) | tile;      // for Gp/Nqp/Nkp indexing (raster order)
  const int ty0 = (tile >> 4) << 4, tx0 = (tile & 15) << 4;
  const float* xb = x + (size_t)b * 64 * HW;

  for (int i = tid; i < 64 * 324; i += 256) {
    int c = i / 324, p = i - c * 324;
    int hy = p / 18, hx = p - hy * 18;
    int gy = ty0 + hy - 1, gx = tx0 + hx - 1;
    float v = 0.f;
    if (gy >= 0 && gy < 256 && gx >= 0 && gx < 256)
      v = xb[(size_t)c * HW + gy * WIDTH + gx];
    xh[XH_IDX(p, c >> 3) + (c & 7)] = f2bf(v);
  }
  __syncthreads();
  for (int p = tid; p < 324; p += 256) {
    float s = 0.f, s2 = 0.f;
    #pragma unroll
    for (int g = 0; g < 8; ++g) {
      short8v v8 = *(const short8v*)&xh[XH_IDX(p, g)];
      #pragma unroll
      for (int j = 0; j < 8; ++j) { float v = bf2f((unsigned short)v8[j]); s += v; s2 += v * v; }
    }
    float mean = s * 0.015625f;
    float var = s2 * 0.015625f - mean * mean;
    rsp[p] = rsqrtf(var + 1e-5f);
  }
  __syncthreads();
  for (int i = tid; i < 2592; i += 256) {
    int p = i >> 3;
    float rs = rsp[p];
    short8v v8 = *(const short8v*)&xh[i * 8];
    #pragma unroll
    for (int j = 0; j < 8; ++j) v8[j] = (short)f2bf(bf2f((unsigned short)v8[j]) * rs);
    *(short8v*)&xh[i * 8] = v8;
  }
  __syncthreads();

  const int lane = tid & 63;
  const int wid = tid >> 6;
  const int fcol = lane & 15;
  const int fk = lane >> 4;
  const int dpy = (tid >> 2) & 15;
  const int dg = tid & 3;

  auto gemm32 = [&](int qb, int kb) {
    short8v bq[2], bk[2];
    const float* wrq = w1 + (size_t)(qb + fcol) * 64;
    const float* wrk = w1 + (size_t)(kb + fcol) * 64;
    #pragma unroll
    for (int s = 0; s < 2; ++s) {
      int cs = fk * 8 + s * 32;
      #pragma unroll
      for (int j = 0; j < 8; ++j) {
        float lw = ln2w[cs + j];
        bq[s][j] = (short)f2bf(wrq[cs + j] * lw);
        bk[s][j] = (short)f2bf(wrk[cs + j] * lw);
      }
    }
    for (int t = wid; t < 21; t += 4) {
      int ar = t * 16 + fcol;
      short8v a0, a1;
      if (ar < 324) {
        a0 = *(const short8v*)&xh[XH_IDX(ar, fk)];
        a1 = *(const short8v*)&xh[XH_IDX(ar, fk + 4)];
      } else {
        short8v z = {0,0,0,0,0,0,0,0};
        a0 = z; a1 = z;
      }
      f32x4 aq = {0.f, 0.f, 0.f, 0.f};
      f32x4 ak = {0.f, 0.f, 0.f, 0.f};
      aq = __builtin_amdgcn_mfma_f32_16x16x32_bf16(a0, bq[0], aq, 0, 0, 0);
      aq = __builtin_amdgcn_mfma_f32_16x16x32_bf16(a1, bq[1], aq, 0, 0, 0);
      ak = __builtin_amdgcn_mfma_f32_16x16x32_bf16(a0, bk[0], ak, 0, 0, 0);
      ak = __builtin_amdgcn_mfma_f32_16x16x32_bf16(a1, bk[1], ak, 0, 0, 0);
      #pragma unroll
      for (int r = 0; r < 4; ++r) {
        int px = t * 16 + fk * 4 + r;
        if (px < 324) {
          int hy = px / 18, hx = px - hy * 18;
          tb[fcol * 360 + hy * 20 + hx]        = f2bf(aq[r]);
          tb[(16 + fcol) * 360 + hy * 20 + hx] = f2bf(ak[r]);
        }
      }
    }
  };

  float dout8[8][4];
  auto dw32 = [&](int qwb, int kwb) {
    #pragma unroll
    for (int oc8 = 0; oc8 < 8; ++oc8) {
      int oc = wid * 8 + oc8;
      int ch = (oc < 16) ? (qwb + oc) : (kwb + oc - 16);
      const float* w9 = wdw + (size_t)ch * 9;
      float wk[9];
      #pragma unroll
      for (int t = 0; t < 9; ++t) wk[t] = w9[t];
      float a0 = 0.f, a1 = 0.f, a2 = 0.f, a3 = 0.f;
      #pragma unroll
      for (int ky = 0; ky < 3; ++ky) {
        int base = oc * 360 + (dpy + ky) * 20 + dg * 4;
        short4v t4 = *(const short4v*)&tb[base];
        unsigned int t2 = *(const unsigned int*)&tb[base + 4];
        float e0 = bf2f((unsigned short)t4[0]);
        float e1 = bf2f((unsigned short)t4[1]);
        float e2 = bf2f((unsigned short)t4[2]);
        float e3 = bf2f((unsigned short)t4[3]);
        float e4 = bf2f((unsigned short)(t2 & 0xffff));
        float e5 = bf2f((unsigned short)(t2 >> 16));
        float k0 = wk[ky*3+0], k1 = wk[ky*3+1], k2 = wk[ky*3+2];
        a0 += k0*e0 + k1*e1 + k2*e2;
        a1 += k0*e1 + k1*e2 + k2*e3;
        a2 += k0*e2 + k1*e3 + k2*e4;
        a3 += k0*e3 + k1*e4 + k2*e5;
      }
      dout8[oc8][0] = a0; dout8[oc8][1] = a1;
      dout8[oc8][2] = a2; dout8[oc8][3] = a3;
    }
  };

  for (int n = 0; n < 4; ++n) {
    gemm32(16 * n, 64 + 16 * n);
    __syncthreads();
    dw32(16 * n, 64 + 16 * n);
    #pragma unroll
    for (int oc8 = 0; oc8 < 8; ++oc8) {
      int oc = wid * 8 + oc8;
      unsigned short* dst = (oc < 16) ? qc : kc;
      int row = oc & 15;
      #pragma unroll
      for (int i = 0; i < 4; ++i)
        dst[QC_IDX(row, dpy*16 + dg*4 + i)] = f2bf(dout8[oc8][i]);
    }
    __syncthreads();
    {
      int ch = tid >> 4, seg = tid & 15;
      float sq = 0.f, sk = 0.f;
      #pragma unroll
      for (int j = 0; j < 16; ++j) {
        float vq = bf2f(qc[QC_IDX(ch, seg * 16 + j)]); sq += vq * vq;
        float vk = bf2f(kc[QC_IDX(ch, seg * 16 + j)]); sk += vk * vk;
      }
      sq += __shfl_xor(sq, 1); sq += __shfl_xor(sq, 2); sq += __shfl_xor(sq, 4); sq += __shfl_xor(sq, 8);
      sk += __shfl_xor(sk, 1); sk += __shfl_xor(sk, 2); sk += __shfl_xor(sk, 4); sk += __shfl_xor(sk, 8);
      if (seg == 0) {
        Nqp[(size_t)blk * 64 + n * 16 + ch] = sq;
        Nkp[(size_t)blk * 64 + n * 16 + ch] = sk;
      }
    }
    if (wid == 0) {
      f32x4 g = {0.f, 0.f, 0.f, 0.f};
      #pragma unroll
      for (int s = 0; s < 8; ++s) {
        int G = fk + 4 * s;
        short8v aq = *(const short8v*)&qc[QCG_IDX(fcol, G)];
        short8v bk = *(const short8v*)&kc[QCG_IDX(fcol, G)];
        g = __builtin_amdgcn_mfma_f32_16x16x32_bf16(aq, bk, g, 0, 0, 0);
      }
      float* gp = Gp + ((size_t)blk * 4 + n) * 256;
      #pragma unroll
      for (int r = 0; r < 4; ++r) gp[(fk * 4 + r) * 16 + fcol] = g[r];
    }
  }
  const float* ib = illu + (size_t)b * 64 * HW;
  for (int j = 0; j < 2; ++j) {
    gemm32(128 + 32 * j, 144 + 32 * j);
    __syncthreads();
    dw32(128 + 32 * j, 144 + 32 * j);
    int gy = ty0 + dpy, gx = tx0 + dg * 4;
    size_t ppos = (size_t)gy * WIDTH + gx;
    #pragma unroll
    for (int oc8 = 0; oc8 < 8; ++oc8) {
      int vc = 32 * j + wid * 8 + oc8;
      float4 iv4 = *(const float4*)&ib[(size_t)vc * HW + ppos];
      unsigned int lo = (unsigned)f2bf(dout8[oc8][0] * iv4.x)
                      | ((unsigned)f2bf(dout8[oc8][1] * iv4.y) << 16);
      unsigned int hi = (unsigned)f2bf(dout8[oc8][2] * iv4.z)
                      | ((unsigned)f2bf(dout8[oc8][3] * iv4.w) << 16);
      uint2 pk; pk.x = lo; pk.y = hi;
      *(uint2*)&vm[((size_t)b * 64 + vc) * HW + ppos] = pk;
    }
    __syncthreads();
  }
}

// ================= fused kernel: XCD-coherent 1:2 role interleave =================
// Per XCD: j in [0,384). j%3==2 -> spatial (128 subs x 8 windows), else chan
// (256 tiles). Spatial blocks run ~2x longer -> time-weighted residency ~1:1.
__global__ __launch_bounds__(256, 2) void k_fused(
    const float* __restrict__ x, const float* __restrict__ illu,
    const float* __restrict__ ln1w, const float* __restrict__ ln2w,
    const float* __restrict__ wqkv, const float* __restrict__ bqkv,
    const float* __restrict__ rpb, const float* __restrict__ wproj,
    const float* __restrict__ bproj, const float* __restrict__ w1,
    const float* __restrict__ wdw,
    float* __restrict__ out, unsigned short* __restrict__ sp, int use_sp,
    unsigned short* __restrict__ vm, float* __restrict__ Gp,
    float* __restrict__ Nqp, float* __restrict__ Nkp)
{
  __shared__ __align__(16) unsigned char smem[80896];
  const int xcd = blockIdx.x & 7;
  const int j = blockIdx.x >> 3;      // 0..383
  const int q3 = j / 3, r3 = j - q3 * 3;
  if (r3 == 2)
    spatial_body(smem, xcd, q3, x, illu, ln1w, wqkv, bqkv, rpb, wproj, bproj, out, sp, use_sp);
  else
    chan_body(smem, xcd, q3 * 2 + r3, x, illu, ln2w, w1, wdw, vm, Gp, Nqp, Nkp);
}

// ---------------- two-stage reduction -> softmax -> fold w_out into M ----------------
__global__ __launch_bounds__(256) void k_reduce1(
    const float* __restrict__ Gp, const float* __restrict__ Nqp, const float* __restrict__ Nkp,
    float* __restrict__ G2, float* __restrict__ Nq2, float* __restrict__ Nk2)
{
  const int blk = blockIdx.x;
  const int b = blk >> 5, g = blk & 31;
  const int tid = threadIdx.x;
  float ga[4] = {0.f, 0.f, 0.f, 0.f};
  for (int t = 0; t < 8; ++t) {
    const float* src = Gp + ((size_t)(b * 256 + g * 8 + t)) * 1024;
    #pragma unroll
    for (int j = 0; j < 4; ++j) ga[j] += src[tid + j * 256];
  }
  float* dst = G2 + ((size_t)(b * 32 + g)) * 1024;
  #pragma unroll
  for (int j = 0; j < 4; ++j) dst[tid + j * 256] = ga[j];
  if (tid < 128) {
    int ch = tid & 63; bool isq = tid < 64;
    const float* np = isq ? Nqp : Nkp;
    float s = 0.f;
    for (int t = 0; t < 8; ++t) s += np[((size_t)(b * 256 + g * 8 + t)) * 64 + ch];
    (isq ? Nq2 : Nk2)[(size_t)(b * 32 + g) * 64 + ch] = s;
  }
}

__global__ __launch_bounds__(256) void k_reduce2(
    const float* __restrict__ G2, const float* __restrict__ Nq2, const float* __restrict__ Nk2,
    const float* __restrict__ temp, const float* __restrict__ wout, float* __restrict__ M)
{
  __shared__ float Gs[1024];
  __shared__ float As[4][16][17];
  __shared__ float nq[64], nk[64];
  const int b = blockIdx.x;
  const int tid = threadIdx.x;
  float ga[4] = {0.f, 0.f, 0.f, 0.f};
  for (int g = 0; g < 32; ++g) {
    const float* src = G2 + ((size_t)(b * 32 + g)) * 1024;
    #pragma unroll
    for (int j = 0; j < 4; ++j) ga[j] += src[tid + j * 256];
  }
  #pragma unroll
  for (int j = 0; j < 4; ++j) Gs[tid + j * 256] = ga[j];
  if (tid < 128) {
    int ch = tid & 63; bool isq = tid < 64;
    const float* n2 = isq ? Nq2 : Nk2;
    float s = 0.f;
    for (int g = 0; g < 32; ++g) s += n2[(size_t)(b * 32 + g) * 64 + ch];
    float r = fmaxf(sqrtf(s), 1e-12f);
    (isq ? nq : nk)[ch] = r;
  }
  __syncthreads();
  if (tid < 64) {
    int n = tid >> 4, d = tid & 15;
    float tv = temp[n];
    float row[16]; float mx = -1e30f;
    #pragma unroll
    for (int e = 0; e < 16; ++e) {
      float v = Gs[n * 256 + d * 16 + e] / (nq[n * 16 + d] * nk[n * 16 + e]) * tv;
      row[e] = v; mx = fmaxf(mx, v);
    }
    float s = 0.f;
    #pragma unroll
    for (int e = 0; e < 16; ++e) { float ev = __expf(row[e] - mx); row[e] = ev; s += ev; }
    float inv = 1.f / s;
    #pragma unroll
    for (int e = 0; e < 16; ++e) As[n][d][e] = row[e] * inv;
  }
  __syncthreads();
  float* Mb = M + (size_t)b * 4096;
  for (int i = tid; i < 4096; i += 256) {
    int o = i >> 6, cp = i & 63;
    int n = cp >> 4, e = cp & 15;
    float a = 0.f;
    #pragma unroll
    for (int d = 0; d < 16; ++d) a += wout[o * 64 + n * 16 + d] * As[n][d][e];
    Mb[i] = a;
  }
}

// ---------------- apply M to vm; combine with spatial blob; write out ----------------
__global__ __launch_bounds__(256, 3) void k_mdta_out(
    const unsigned short* __restrict__ vm, const float* __restrict__ M,
    const unsigned short* __restrict__ sp, int use_sp,
    float* __restrict__ out)
{
  __shared__ __align__(16) float Ml[4096];
  __shared__ __align__(16) unsigned short spl[64 * 264];
  const int blk = blockIdx.x;
  const int b = blk >> 8;
  const int y = blk & 255;
  const int tid = threadIdx.x;

  const float* Mb = M + (size_t)b * 4096;
  for (int i = tid; i < 4096; i += 256) Ml[i] = Mb[i];
  if (use_sp) {
    int wy = y >> 3, py = y & 7;
    const unsigned short* spb = sp + ((((size_t)b * 1024 + wy * 32) * 8) + py) * 512;
    for (int k = 0; k < 8; ++k) {
      int i3 = k * 256 + tid;
      int o = i3 & 63, wx = i3 >> 6;
      short8v v8 = *(const short8v*)&spb[(size_t)wx * 4096 + o * 8];
      *(short8v*)&spl[o * 264 + wx * 8] = v8;
    }
  }
  __syncthreads();
  float xcol[64];
  const unsigned short* vb = vm + (size_t)b * 64 * HW + y * 256 + tid;
  #pragma unroll
  for (int c = 0; c < 64; ++c) xcol[c] = bf2f(vb[(size_t)c * HW]);
  float* ob = out + (size_t)b * 64 * HW + y * 256 + tid;
  for (int o = 0; o < 64; ++o) {
    const float4* mr = (const float4*)&Ml[o * 64];
    float acc = 0.f;
    #pragma unroll
    for (int g = 0; g < 16; ++g) {
      float4 m4 = mr[g];
      acc += m4.x * xcol[g*4] + m4.y * xcol[g*4+1] + m4.z * xcol[g*4+2] + m4.w * xcol[g*4+3];
    }
    if (use_sp) ob[(size_t)o * HW] = bf2f(spl[o * 264 + tid]) + acc;
    else        ob[(size_t)o * HW] += acc;
  }
}

extern "C" void kernel_launch(void* const* d_in, const int* in_sizes, int n_in,
                              void* d_out, int out_size, void* d_ws, size_t ws_size,
                              hipStream_t stream) {
  const float* x     = (const float*)d_in[0];
  const float* illu  = (const float*)d_in[1];
  const float* ln1w  = (const float*)d_in[2];
  const float* ln2w  = (const float*)d_in[3];
  const float* wqkv  = (const float*)d_in[4];
  const float* bqkv  = (const float*)d_in[5];
  const float* rpb   = (const float*)d_in[6];
  const float* wproj = (const float*)d_in[7];
  const float* bproj = (const float*)d_in[8];
  const float* temp  = (const float*)d_in[9];
  const float* w1    = (const float*)d_in[10];
  const float* wdw   = (const float*)d_in[11];
  const float* wout  = (const float*)d_in[12];
  float* out = (float*)d_out;

  char* ws = (char*)d_ws;
  unsigned short* vm = (unsigned short*)ws;            // 67,108,864 B
  float* Gp  = (float*)(ws + 67108864);                //  8,388,608 B
  float* Nqp = (float*)(ws + 75497472);                //    524,288 B
  float* Nkp = (float*)(ws + 76021760);                //    524,288 B
  float* G2  = (float*)(ws + 76546048);                //  1,048,576 B
  float* Nq2 = (float*)(ws + 77594624);                //     65,536 B
  float* Nk2 = (float*)(ws + 77660160);                //     65,536 B
  float* M   = (float*)(ws + 77725696);                //    131,072 B
  unsigned short* sp = (unsigned short*)(ws + SP_OFF); // 67,108,864 B (if available)
  int use_sp = (ws_size >= SP_OFF + 67108864ull) ? 1 : 0;

  k_fused<<<3072, 256, 0, stream>>>(x, illu, ln1w, ln2w, wqkv, bqkv, rpb, wproj, bproj,
                                    w1, wdw, out, sp, use_sp, vm, Gp, Nqp, Nkp);
  k_reduce1<<<256, 256, 0, stream>>>(Gp, Nqp, Nkp, G2, Nq2, Nk2);
  k_reduce2<<<8, 256, 0, stream>>>(G2, Nq2, Nk2, temp, wout, M);
  k_mdta_out<<<2048, 256, 0, stream>>>(vm, M, sp, use_sp, out);
}

// Round 19
// 644.301 us; speedup vs baseline: 1.0664x; 1.0664x over previous
//
#include <hip/hip_runtime.h>
#include <hip/hip_bf16.h>

#define HW 65536
#define WIDTH 256
#define SP_OFF 77856768ull   // ws offset of spatial-out blob (67,108,864 B bf16)

typedef __attribute__((ext_vector_type(8))) short short8v;
typedef __attribute__((ext_vector_type(4))) short short4v;
typedef __attribute__((ext_vector_type(4))) float f32x4;

__device__ inline float bf2f(unsigned short u) {
  unsigned int i = ((unsigned int)u) << 16;
  float f; __builtin_memcpy(&f, &i, 4); return f;
}
__device__ inline unsigned short f2bf(float x) {
  __hip_bfloat16 h = __float2bfloat16(x);
  unsigned short u; __builtin_memcpy(&u, &h, 2); return u;
}

// swizzled LDS indexers for chan body (granule = 8 bf16 = 16B)
#define XH_IDX(p, g) ((p)*64 + ((((g) ^ ((p)&7)))<<3))
#define QC_IDX(ch, px) ((ch)*256 + ((((px)>>3) ^ ((ch)&7))<<3) + ((px)&7))
#define QCG_IDX(ch, G) ((ch)*256 + ((((G) ^ ((ch)&7)))<<3))

// ================= spatial body =================
// LDS map: shbuf 0..18432 | ks ..27648 | vs ..36864 | vsT ..46080 (rs_tok aliases
// first 256B of vsT; disjoint lifetimes) | biasx ..80896 ([4][64][68] bf16)
__device__ __forceinline__ void spatial_body(
    unsigned char* smem, int b, int grp,
    const float* __restrict__ x, const float* __restrict__ illu,
    const float* __restrict__ ln1w, const float* __restrict__ wqkv,
    const float* __restrict__ bqkv, const float* __restrict__ rpb,
    const float* __restrict__ wproj, const float* __restrict__ bproj,
    float* __restrict__ out, unsigned short* __restrict__ sp, int use_sp)
{
  unsigned short* shbuf = (unsigned short*)smem;            // 9216 shorts
  unsigned short* ks    = (unsigned short*)(smem + 18432);
  unsigned short* vs    = (unsigned short*)(smem + 27648);
  unsigned short* vsT   = (unsigned short*)(smem + 36864);
  float* rs_tok         = (float*)(smem + 36864);           // aliases vsT prefix
  unsigned short* biasx = (unsigned short*)(smem + 46080);  // [4][64][68] bf16

  unsigned short* xw = shbuf;
  unsigned short* qs = shbuf + 4608;

  const int tid = threadIdx.x;
  const float* xb = x + (size_t)b * 64 * HW;
  const float* ib = illu + (size_t)b * 64 * HW;

  const int lane = tid & 63;
  const int w = tid >> 6;
  const int fr = lane & 15;
  const int fg = lane >> 4;
  const int hb = w * 16;

  // expand relative-position bias once per block: biasx[w][q][k]
  for (int i = tid; i < 16384; i += 256) {
    int w4 = i >> 12, q = (i >> 6) & 63, k = i & 63;
    int ridx = ((q >> 3) - (k >> 3) + 7) * 15 + ((q & 7) - (k & 7) + 7);
    biasx[(w4 * 64 + q) * 68 + k] = f2bf(rpb[ridx * 4 + w4]);
  }

  short8v bfq[3][2];
  float biasr[3];
  #pragma unroll
  for (int part = 0; part < 3; ++part) {
    int o = part * 64 + hb + fr;
    biasr[part] = bqkv[o];
    #pragma unroll
    for (int kh = 0; kh < 2; ++kh)
      #pragma unroll
      for (int j = 0; j < 8; ++j) {
        int c = kh * 32 + fg * 8 + j;
        bfq[part][kh][j] = (short)f2bf(wqkv[c * 192 + o] * ln1w[c]);
      }
  }
  short8v bfp[2];
  #pragma unroll
  for (int kh = 0; kh < 2; ++kh)
    #pragma unroll
    for (int j = 0; j < 8; ++j) {
      int c = kh * 32 + fg * 8 + j;
      bfp[kh][j] = (short)f2bf(wproj[c * 64 + hb + fr]);
    }

  for (int wi = 0; wi < 4; ++wi) {
    const int win = (grp << 2) + wi;
    const int h0 = (win >> 5) << 3;
    const int w0 = (win & 31) << 3;

    for (int i = tid; i < 1024; i += 256) {
      int c = i >> 4, seg = i & 15;
      int row = seg >> 1, half = (seg & 1) * 4;
      float4 v4 = *(const float4*)&xb[(size_t)c * HW + (h0 + row) * WIDTH + w0 + half];
      int p = row * 8 + half;
      xw[(p+0)*72 + c] = f2bf(v4.x);
      xw[(p+1)*72 + c] = f2bf(v4.y);
      xw[(p+2)*72 + c] = f2bf(v4.z);
      xw[(p+3)*72 + c] = f2bf(v4.w);
    }
    __syncthreads();
    {
      int l = tid >> 2, q4 = tid & 3;
      short8v v8a = *(const short8v*)&xw[l*72 + q4*16];
      short8v v8b = *(const short8v*)&xw[l*72 + q4*16 + 8];
      float s = 0.f, s2 = 0.f;
      #pragma unroll
      for (int j = 0; j < 8; ++j) {
        float va = bf2f((unsigned short)v8a[j]), vb = bf2f((unsigned short)v8b[j]);
        s += va + vb; s2 += va * va + vb * vb;
      }
      s += __shfl_down(s, 1); s2 += __shfl_down(s2, 1);
      s += __shfl_down(s, 2); s2 += __shfl_down(s2, 2);
      if (q4 == 0) {
        float mean = s * 0.015625f;
        float var = s2 * 0.015625f - mean * mean;
        rs_tok[l] = rsqrtf(var + 1e-5f);
      }
    }
    __syncthreads();
    // qkv via MFMA (B-frags in registers)
    {
      short8v a[4][2];
      #pragma unroll
      for (int rt = 0; rt < 4; ++rt)
        #pragma unroll
        for (int kh = 0; kh < 2; ++kh)
          a[rt][kh] = *(const short8v*)&xw[(rt*16 + fr)*72 + kh*32 + fg*8];
      #pragma unroll
      for (int part = 0; part < 3; ++part) {
        float bias = biasr[part];
        #pragma unroll
        for (int rt = 0; rt < 4; ++rt) {
          f32x4 acc = {0.f, 0.f, 0.f, 0.f};
          acc = __builtin_amdgcn_mfma_f32_16x16x32_bf16(a[rt][0], bfq[part][0], acc, 0, 0, 0);
          acc = __builtin_amdgcn_mfma_f32_16x16x32_bf16(a[rt][1], bfq[part][1], acc, 0, 0, 0);
          #pragma unroll
          for (int r = 0; r < 4; ++r) {
            int t = rt*16 + fg*4 + r;
            float val = acc[r] * rs_tok[t] + bias;
            if (part == 0)      qs[t*72 + hb + fr] = f2bf(val * 0.25f);
            else if (part == 1) ks[t*72 + hb + fr] = f2bf(val);
            else                vs[t*72 + hb + fr] = f2bf(val);
          }
        }
      }
    }
    __syncthreads();
    // stage illu -> xw
    for (int i = tid; i < 1024; i += 256) {
      int c = i >> 4, seg = i & 15;
      int row = seg >> 1, half = (seg & 1) * 4;
      float4 v4 = *(const float4*)&ib[(size_t)c * HW + (h0 + row) * WIDTH + w0 + half];
      int p = row * 8 + half;
      xw[(p+0)*72 + c] = f2bf(v4.x);
      xw[(p+1)*72 + c] = f2bf(v4.y);
      xw[(p+2)*72 + c] = f2bf(v4.z);
      xw[(p+3)*72 + c] = f2bf(v4.w);
    }
    __syncthreads();
    // modulate V, build swizzled V^T (vsT prefix overwrites rs_tok alias: dead now)
    for (int i = tid; i < 4096; i += 256) {
      int l = i >> 6, c = i & 63;
      unsigned short vb16 = f2bf(bf2f(vs[l*72 + c]) * bf2f(xw[l*72 + c]));
      vs[l*72 + c] = vb16;
      vsT[c*72 + ((((l >> 3) ^ (c & 7)) << 3) | (l & 7))] = vb16;
    }
    __syncthreads();
    // attention: S^T = mfma(K,Q), softmax in regs, PV via P-buffers in shbuf
    float inv_s[4];
    {
      short8v zero8 = {0,0,0,0,0,0,0,0};
      short8v kf[4], qf[4];
      #pragma unroll
      for (int t = 0; t < 4; ++t) {
        if (fg < 2) {
          kf[t] = *(const short8v*)&ks[(t*16 + fr)*72 + hb + fg*8];
          qf[t] = *(const short8v*)&qs[(t*16 + fr)*72 + hb + fg*8];
        } else { kf[t] = zero8; qf[t] = zero8; }
      }
      f32x4 st[4][4];
      #pragma unroll
      for (int kt = 0; kt < 4; ++kt)
        #pragma unroll
        for (int qt = 0; qt < 4; ++qt) {
          f32x4 z = {0.f, 0.f, 0.f, 0.f};
          st[kt][qt] = __builtin_amdgcn_mfma_f32_16x16x32_bf16(kf[kt], qf[qt], z, 0, 0, 0);
        }
      float sc[4][16];
      #pragma unroll
      for (int qt = 0; qt < 4; ++qt) {
        const unsigned short* brow = &biasx[(w * 64 + qt * 16 + fr) * 68];
        float mx = -1e30f;
        #pragma unroll
        for (int kt = 0; kt < 4; ++kt) {
          short4v b4 = *(const short4v*)&brow[kt * 16 + fg * 4];
          #pragma unroll
          for (int r = 0; r < 4; ++r) {
            float v = st[kt][qt][r] + bf2f((unsigned short)b4[r]);
            sc[qt][kt*4 + r] = v;
            mx = fmaxf(mx, v);
          }
        }
        mx = fmaxf(mx, __shfl_xor(mx, 16));
        mx = fmaxf(mx, __shfl_xor(mx, 32));
        float ss = 0.f;
        #pragma unroll
        for (int j = 0; j < 16; ++j) { float e = __expf(sc[qt][j] - mx); sc[qt][j] = e; ss += e; }
        ss += __shfl_xor(ss, 16);
        ss += __shfl_xor(ss, 32);
        inv_s[qt] = 1.f / ss;
      }
      __syncthreads();
      unsigned short* pb = shbuf + w * 2304;
      f32x4 ot[4];
      #pragma unroll
      for (int nt = 0; nt < 4; ++nt) { f32x4 z = {0.f,0.f,0.f,0.f}; ot[nt] = z; }
      #pragma unroll
      for (int P = 0; P < 2; ++P) {
        #pragma unroll
        for (int qt = 0; qt < 4; ++qt)
          #pragma unroll
          for (int k2 = 0; k2 < 2; ++k2) {
            int kt = 2*P + k2;
            unsigned int lo = (unsigned)f2bf(sc[qt][kt*4+0]) | ((unsigned)f2bf(sc[qt][kt*4+1]) << 16);
            unsigned int hi = (unsigned)f2bf(sc[qt][kt*4+2]) | ((unsigned)f2bf(sc[qt][kt*4+3]) << 16);
            uint2 pk; pk.x = lo; pk.y = hi;
            *(uint2*)&pb[(qt*16 + fr)*36 + k2*16 + fg*4] = pk;
          }
        __syncthreads();
        short8v av = *(const short8v*)&vsT[(hb + fr)*72 + (((P*4 + fg) ^ ((hb + fr) & 7)) << 3)];
        #pragma unroll
        for (int nt = 0; nt < 4; ++nt) {
          short4v p0 = *(const short4v*)&pb[(nt*16 + fr)*36 + fg*8];
          short4v p1 = *(const short4v*)&pb[(nt*16 + fr)*36 + fg*8 + 4];
          short8v bv;
          #pragma unroll
          for (int j = 0; j < 4; ++j) { bv[j] = p0[j]; bv[4+j] = p1[j]; }
          ot[nt] = __builtin_amdgcn_mfma_f32_16x16x32_bf16(av, bv, ot[nt], 0, 0, 0);
        }
        __syncthreads();
      }
      #pragma unroll
      for (int nt = 0; nt < 4; ++nt) {
        float iv = inv_s[nt];
        unsigned int lo = (unsigned)f2bf(ot[nt][0]*iv) | ((unsigned)f2bf(ot[nt][1]*iv) << 16);
        unsigned int hi = (unsigned)f2bf(ot[nt][2]*iv) | ((unsigned)f2bf(ot[nt][3]*iv) << 16);
        uint2 pk; pk.x = lo; pk.y = hi;
        *(uint2*)&ks[(nt*16 + fr)*72 + hb + fg*4] = pk;
      }
    }
    __syncthreads();
    // proj (B-frag in registers); result -> vs
    {
      short8v a[4][2];
      #pragma unroll
      for (int rt = 0; rt < 4; ++rt)
        #pragma unroll
        for (int kh = 0; kh < 2; ++kh)
          a[rt][kh] = *(const short8v*)&ks[(rt*16 + fr)*72 + kh*32 + fg*8];
      #pragma unroll
      for (int rt = 0; rt < 4; ++rt) {
        f32x4 acc = {0.f, 0.f, 0.f, 0.f};
        acc = __builtin_amdgcn_mfma_f32_16x16x32_bf16(a[rt][0], bfp[0], acc, 0, 0, 0);
        acc = __builtin_amdgcn_mfma_f32_16x16x32_bf16(a[rt][1], bfp[1], acc, 0, 0, 0);
        #pragma unroll
        for (int r = 0; r < 4; ++r)
          vs[(rt*16 + fg*4 + r)*72 + hb + fr] = f2bf(acc[r]);
      }
    }
    __syncthreads();
    if (use_sp) {
      unsigned short* spw = sp + (size_t)(b * 1024 + win) * 4096;
      for (int i = tid; i < 1024; i += 256) {
        int row = i >> 7, rem = i & 127;
        int c = rem >> 1, half = (rem & 1) * 4;
        int p = row * 8 + half;
        size_t gofs = (size_t)c * HW + (h0 + row) * WIDTH + w0 + half;
        float4 xr4 = *(const float4*)&xb[gofs];
        float bp = bproj[c];
        unsigned int lo = (unsigned)f2bf(xr4.x + bp + bf2f(vs[(p+0)*72 + c]))
                        | ((unsigned)f2bf(xr4.y + bp + bf2f(vs[(p+1)*72 + c])) << 16);
        unsigned int hi = (unsigned)f2bf(xr4.z + bp + bf2f(vs[(p+2)*72 + c]))
                        | ((unsigned)f2bf(xr4.w + bp + bf2f(vs[(p+3)*72 + c])) << 16);
        uint2 pk; pk.x = lo; pk.y = hi;
        *(uint2*)&spw[row*512 + c*8 + half] = pk;
      }
    } else {
      for (int i = tid; i < 1024; i += 256) {
        int o = i >> 4, seg = i & 15;
        int row = seg >> 1, half = (seg & 1) * 4;
        int p = row * 8 + half;
        size_t gofs = (size_t)o * HW + (h0 + row) * WIDTH + w0 + half;
        float4 xr4 = *(const float4*)&xb[gofs];
        float bp = bproj[o];
        float4 r;
        r.x = xr4.x + bp + bf2f(vs[(p+0)*72 + o]);
        r.y = xr4.y + bp + bf2f(vs[(p+1)*72 + o]);
        r.z = xr4.z + bp + bf2f(vs[(p+2)*72 + o]);
        r.w = xr4.w + bp + bf2f(vs[(p+3)*72 + o]);
        *(float4*)&out[(size_t)b * 64 * HW + gofs] = r;
      }
    }
    __syncthreads();
  }
}

// ================= channel body (round-9 structure; b = XCD, tile sequential) =================
__device__ __forceinline__ void chan_body(
    unsigned char* smem, int b, int tile,
    const float* __restrict__ x, const float* __restrict__ illu,
    const float* __restrict__ ln2w, const float* __restrict__ w1,
    const float* __restrict__ wdw,
    unsigned short* __restrict__ vm, float* __restrict__ Gp,
    float* __restrict__ Nqp, float* __restrict__ Nkp)
{
  unsigned short* xh = (unsigned short*)smem;             // 324*64 shorts (41472B)
  unsigned short* tb = (unsigned short*)(smem + 41472);   // 32*360 shorts (23040B)
  unsigned short* qc = (unsigned short*)(smem + 64512);   // 16*256 shorts
  unsigned short* kc = (unsigned short*)(smem + 72704);   // 16*256 shorts
  float* rsp = (float*)tb;   // scratch alias, dead before tb's first gemm write

  const int tid = threadIdx.x;
  const int blk = (b << 8) | tile;      // for Gp/Nqp/Nkp indexing (raster order)
  const int ty0 = (tile >> 4) << 4, tx0 = (tile & 15) << 4;
  const float* xb = x + (size_t)b * 64 * HW;

  for (int i = tid; i < 64 * 324; i += 256) {
    int c = i / 324, p = i - c * 324;
    int hy = p / 18, hx = p - hy * 18;
    int gy = ty0 + hy - 1, gx = tx0 + hx - 1;
    float v = 0.f;
    if (gy >= 0 && gy < 256 && gx >= 0 && gx < 256)
      v = xb[(size_t)c * HW + gy * WIDTH + gx];
    xh[XH_IDX(p, c >> 3) + (c & 7)] = f2bf(v);
  }
  __syncthreads();
  for (int p = tid; p < 324; p += 256) {
    float s = 0.f, s2 = 0.f;
    #pragma unroll
    for (int g = 0; g < 8; ++g) {
      short8v v8 = *(const short8v*)&xh[XH_IDX(p, g)];
      #pragma unroll
      for (int j = 0; j < 8; ++j) { float v = bf2f((unsigned short)v8[j]); s += v; s2 += v * v; }
    }
    float mean = s * 0.015625f;
    float var = s2 * 0.015625f - mean * mean;
    rsp[p] = rsqrtf(var + 1e-5f);
  }
  __syncthreads();
  for (int i = tid; i < 2592; i += 256) {
    int p = i >> 3;
    float rs = rsp[p];
    short8v v8 = *(const short8v*)&xh[i * 8];
    #pragma unroll
    for (int j = 0; j < 8; ++j) v8[j] = (short)f2bf(bf2f((unsigned short)v8[j]) * rs);
    *(short8v*)&xh[i * 8] = v8;
  }
  __syncthreads();

  const int lane = tid & 63;
  const int wid = tid >> 6;
  const int fcol = lane & 15;
  const int fk = lane >> 4;
  const int dpy = (tid >> 2) & 15;
  const int dg = tid & 3;

  auto gemm32 = [&](int qb, int kb) {
    short8v bq[2], bk[2];
    const float* wrq = w1 + (size_t)(qb + fcol) * 64;
    const float* wrk = w1 + (size_t)(kb + fcol) * 64;
    #pragma unroll
    for (int s = 0; s < 2; ++s) {
      int cs = fk * 8 + s * 32;
      #pragma unroll
      for (int j = 0; j < 8; ++j) {
        float lw = ln2w[cs + j];
        bq[s][j] = (short)f2bf(wrq[cs + j] * lw);
        bk[s][j] = (short)f2bf(wrk[cs + j] * lw);
      }
    }
    for (int t = wid; t < 21; t += 4) {
      int ar = t * 16 + fcol;
      short8v a0, a1;
      if (ar < 324) {
        a0 = *(const short8v*)&xh[XH_IDX(ar, fk)];
        a1 = *(const short8v*)&xh[XH_IDX(ar, fk + 4)];
      } else {
        short8v z = {0,0,0,0,0,0,0,0};
        a0 = z; a1 = z;
      }
      f32x4 aq = {0.f, 0.f, 0.f, 0.f};
      f32x4 ak = {0.f, 0.f, 0.f, 0.f};
      aq = __builtin_amdgcn_mfma_f32_16x16x32_bf16(a0, bq[0], aq, 0, 0, 0);
      aq = __builtin_amdgcn_mfma_f32_16x16x32_bf16(a1, bq[1], aq, 0, 0, 0);
      ak = __builtin_amdgcn_mfma_f32_16x16x32_bf16(a0, bk[0], ak, 0, 0, 0);
      ak = __builtin_amdgcn_mfma_f32_16x16x32_bf16(a1, bk[1], ak, 0, 0, 0);
      #pragma unroll
      for (int r = 0; r < 4; ++r) {
        int px = t * 16 + fk * 4 + r;
        if (px < 324) {
          int hy = px / 18, hx = px - hy * 18;
          tb[fcol * 360 + hy * 20 + hx]        = f2bf(aq[r]);
          tb[(16 + fcol) * 360 + hy * 20 + hx] = f2bf(ak[r]);
        }
      }
    }
  };

  float dout8[8][4];
  auto dw32 = [&](int qwb, int kwb) {
    #pragma unroll
    for (int oc8 = 0; oc8 < 8; ++oc8) {
      int oc = wid * 8 + oc8;
      int ch = (oc < 16) ? (qwb + oc) : (kwb + oc - 16);
      const float* w9 = wdw + (size_t)ch * 9;
      float wk[9];
      #pragma unroll
      for (int t = 0; t < 9; ++t) wk[t] = w9[t];
      float a0 = 0.f, a1 = 0.f, a2 = 0.f, a3 = 0.f;
      #pragma unroll
      for (int ky = 0; ky < 3; ++ky) {
        int base = oc * 360 + (dpy + ky) * 20 + dg * 4;
        short4v t4 = *(const short4v*)&tb[base];
        unsigned int t2 = *(const unsigned int*)&tb[base + 4];
        float e0 = bf2f((unsigned short)t4[0]);
        float e1 = bf2f((unsigned short)t4[1]);
        float e2 = bf2f((unsigned short)t4[2]);
        float e3 = bf2f((unsigned short)t4[3]);
        float e4 = bf2f((unsigned short)(t2 & 0xffff));
        float e5 = bf2f((unsigned short)(t2 >> 16));
        float k0 = wk[ky*3+0], k1 = wk[ky*3+1], k2 = wk[ky*3+2];
        a0 += k0*e0 + k1*e1 + k2*e2;
        a1 += k0*e1 + k1*e2 + k2*e3;
        a2 += k0*e2 + k1*e3 + k2*e4;
        a3 += k0*e3 + k1*e4 + k2*e5;
      }
      dout8[oc8][0] = a0; dout8[oc8][1] = a1;
      dout8[oc8][2] = a2; dout8[oc8][3] = a3;
    }
  };

  for (int n = 0; n < 4; ++n) {
    gemm32(16 * n, 64 + 16 * n);
    __syncthreads();
    dw32(16 * n, 64 + 16 * n);
    #pragma unroll
    for (int oc8 = 0; oc8 < 8; ++oc8) {
      int oc = wid * 8 + oc8;
      unsigned short* dst = (oc < 16) ? qc : kc;
      int row = oc & 15;
      #pragma unroll
      for (int i = 0; i < 4; ++i)
        dst[QC_IDX(row, dpy*16 + dg*4 + i)] = f2bf(dout8[oc8][i]);
    }
    __syncthreads();
    {
      int ch = tid >> 4, seg = tid & 15;
      float sq = 0.f, sk = 0.f;
      #pragma unroll
      for (int j = 0; j < 16; ++j) {
        float vq = bf2f(qc[QC_IDX(ch, seg * 16 + j)]); sq += vq * vq;
        float vk = bf2f(kc[QC_IDX(ch, seg * 16 + j)]); sk += vk * vk;
      }
      sq += __shfl_xor(sq, 1); sq += __shfl_xor(sq, 2); sq += __shfl_xor(sq, 4); sq += __shfl_xor(sq, 8);
      sk += __shfl_xor(sk, 1); sk += __shfl_xor(sk, 2); sk += __shfl_xor(sk, 4); sk += __shfl_xor(sk, 8);
      if (seg == 0) {
        Nqp[(size_t)blk * 64 + n * 16 + ch] = sq;
        Nkp[(size_t)blk * 64 + n * 16 + ch] = sk;
      }
    }
    if (wid == 0) {
      f32x4 g = {0.f, 0.f, 0.f, 0.f};
      #pragma unroll
      for (int s = 0; s < 8; ++s) {
        int G = fk + 4 * s;
        short8v aq = *(const short8v*)&qc[QCG_IDX(fcol, G)];
        short8v bk = *(const short8v*)&kc[QCG_IDX(fcol, G)];
        g = __builtin_amdgcn_mfma_f32_16x16x32_bf16(aq, bk, g, 0, 0, 0);
      }
      float* gp = Gp + ((size_t)blk * 4 + n) * 256;
      #pragma unroll
      for (int r = 0; r < 4; ++r) gp[(fk * 4 + r) * 16 + fcol] = g[r];
    }
  }
  const float* ib = illu + (size_t)b * 64 * HW;
  for (int j = 0; j < 2; ++j) {
    gemm32(128 + 32 * j, 144 + 32 * j);
    __syncthreads();
    dw32(128 + 32 * j, 144 + 32 * j);
    int gy = ty0 + dpy, gx = tx0 + dg * 4;
    size_t ppos = (size_t)gy * WIDTH + gx;
    #pragma unroll
    for (int oc8 = 0; oc8 < 8; ++oc8) {
      int vc = 32 * j + wid * 8 + oc8;
      float4 iv4 = *(const float4*)&ib[(size_t)vc * HW + ppos];
      unsigned int lo = (unsigned)f2bf(dout8[oc8][0] * iv4.x)
                      | ((unsigned)f2bf(dout8[oc8][1] * iv4.y) << 16);
      unsigned int hi = (unsigned)f2bf(dout8[oc8][2] * iv4.z)
                      | ((unsigned)f2bf(dout8[oc8][3] * iv4.w) << 16);
      uint2 pk; pk.x = lo; pk.y = hi;
      *(uint2*)&vm[((size_t)b * 64 + vc) * HW + ppos] = pk;
    }
    __syncthreads();
  }
}

// ================= fused kernel: XCD-coherent role interleave =================
// xcd = bid&7 (dispatch round-robin), j = bid>>3; role = j&1, idx = j>>1.
// Both bodies use batch = xcd -> each XCD's L2 serves exactly one batch.
__global__ __launch_bounds__(256, 2) void k_fused(
    const float* __restrict__ x, const float* __restrict__ illu,
    const float* __restrict__ ln1w, const float* __restrict__ ln2w,
    const float* __restrict__ wqkv, const float* __restrict__ bqkv,
    const float* __restrict__ rpb, const float* __restrict__ wproj,
    const float* __restrict__ bproj, const float* __restrict__ w1,
    const float* __restrict__ wdw,
    float* __restrict__ out, unsigned short* __restrict__ sp, int use_sp,
    unsigned short* __restrict__ vm, float* __restrict__ Gp,
    float* __restrict__ Nqp, float* __restrict__ Nkp)
{
  __shared__ __align__(16) unsigned char smem[80896];
  const int xcd = blockIdx.x & 7;
  const int j = blockIdx.x >> 3;
  const int idx = j >> 1;
  if (j & 1)
    chan_body(smem, xcd, idx, x, illu, ln2w, w1, wdw, vm, Gp, Nqp, Nkp);
  else
    spatial_body(smem, xcd, idx, x, illu, ln1w, wqkv, bqkv, rpb, wproj, bproj, out, sp, use_sp);
}

// ---------------- two-stage reduction -> softmax -> fold w_out into M ----------------
__global__ __launch_bounds__(256) void k_reduce1(
    const float* __restrict__ Gp, const float* __restrict__ Nqp, const float* __restrict__ Nkp,
    float* __restrict__ G2, float* __restrict__ Nq2, float* __restrict__ Nk2)
{
  const int blk = blockIdx.x;
  const int b = blk >> 5, g = blk & 31;
  const int tid = threadIdx.x;
  float ga[4] = {0.f, 0.f, 0.f, 0.f};
  for (int t = 0; t < 8; ++t) {
    const float* src = Gp + ((size_t)(b * 256 + g * 8 + t)) * 1024;
    #pragma unroll
    for (int j = 0; j < 4; ++j) ga[j] += src[tid + j * 256];
  }
  float* dst = G2 + ((size_t)(b * 32 + g)) * 1024;
  #pragma unroll
  for (int j = 0; j < 4; ++j) dst[tid + j * 256] = ga[j];
  if (tid < 128) {
    int ch = tid & 63; bool isq = tid < 64;
    const float* np = isq ? Nqp : Nkp;
    float s = 0.f;
    for (int t = 0; t < 8; ++t) s += np[((size_t)(b * 256 + g * 8 + t)) * 64 + ch];
    (isq ? Nq2 : Nk2)[(size_t)(b * 32 + g) * 64 + ch] = s;
  }
}

__global__ __launch_bounds__(256) void k_reduce2(
    const float* __restrict__ G2, const float* __restrict__ Nq2, const float* __restrict__ Nk2,
    const float* __restrict__ temp, const float* __restrict__ wout, float* __restrict__ M)
{
  __shared__ float Gs[1024];
  __shared__ float As[4][16][17];
  __shared__ float nq[64], nk[64];
  const int b = blockIdx.x;
  const int tid = threadIdx.x;
  float ga[4] = {0.f, 0.f, 0.f, 0.f};
  for (int g = 0; g < 32; ++g) {
    const float* src = G2 + ((size_t)(b * 32 + g)) * 1024;
    #pragma unroll
    for (int j = 0; j < 4; ++j) ga[j] += src[tid + j * 256];
  }
  #pragma unroll
  for (int j = 0; j < 4; ++j) Gs[tid + j * 256] = ga[j];
  if (tid < 128) {
    int ch = tid & 63; bool isq = tid < 64;
    const float* n2 = isq ? Nq2 : Nk2;
    float s = 0.f;
    for (int g = 0; g < 32; ++g) s += n2[(size_t)(b * 32 + g) * 64 + ch];
    float r = fmaxf(sqrtf(s), 1e-12f);
    (isq ? nq : nk)[ch] = r;
  }
  __syncthreads();
  if (tid < 64) {
    int n = tid >> 4, d = tid & 15;
    float tv = temp[n];
    float row[16]; float mx = -1e30f;
    #pragma unroll
    for (int e = 0; e < 16; ++e) {
      float v = Gs[n * 256 + d * 16 + e] / (nq[n * 16 + d] * nk[n * 16 + e]) * tv;
      row[e] = v; mx = fmaxf(mx, v);
    }
    float s = 0.f;
    #pragma unroll
    for (int e = 0; e < 16; ++e) { float ev = __expf(row[e] - mx); row[e] = ev; s += ev; }
    float inv = 1.f / s;
    #pragma unroll
    for (int e = 0; e < 16; ++e) As[n][d][e] = row[e] * inv;
  }
  __syncthreads();
  float* Mb = M + (size_t)b * 4096;
  for (int i = tid; i < 4096; i += 256) {
    int o = i >> 6, cp = i & 63;
    int n = cp >> 4, e = cp & 15;
    float a = 0.f;
    #pragma unroll
    for (int d = 0; d < 16; ++d) a += wout[o * 64 + n * 16 + d] * As[n][d][e];
    Mb[i] = a;
  }
}

// ---------------- apply M to vm; combine with spatial blob; write out ----------------
__global__ __launch_bounds__(256, 3) void k_mdta_out(
    const unsigned short* __restrict__ vm, const float* __restrict__ M,
    const unsigned short* __restrict__ sp, int use_sp,
    float* __restrict__ out)
{
  __shared__ __align__(16) float Ml[4096];
  __shared__ __align__(16) unsigned short spl[64 * 264];
  const int blk = blockIdx.x;
  const int b = blk >> 8;
  const int y = blk & 255;
  const int tid = threadIdx.x;

  const float* Mb = M + (size_t)b * 4096;
  for (int i = tid; i < 4096; i += 256) Ml[i] = Mb[i];
  if (use_sp) {
    int wy = y >> 3, py = y & 7;
    const unsigned short* spb = sp + ((((size_t)b * 1024 + wy * 32) * 8) + py) * 512;
    for (int k = 0; k < 8; ++k) {
      int i3 = k * 256 + tid;
      int o = i3 & 63, wx = i3 >> 6;
      short8v v8 = *(const short8v*)&spb[(size_t)wx * 4096 + o * 8];
      *(short8v*)&spl[o * 264 + wx * 8] = v8;
    }
  }
  __syncthreads();
  float xcol[64];
  const unsigned short* vb = vm + (size_t)b * 64 * HW + y * 256 + tid;
  #pragma unroll
  for (int c = 0; c < 64; ++c) xcol[c] = bf2f(vb[(size_t)c * HW]);
  float* ob = out + (size_t)b * 64 * HW + y * 256 + tid;
  for (int o = 0; o < 64; ++o) {
    const float4* mr = (const float4*)&Ml[o * 64];
    float acc = 0.f;
    #pragma unroll
    for (int g = 0; g < 16; ++g) {
      float4 m4 = mr[g];
      acc += m4.x * xcol[g*4] + m4.y * xcol[g*4+1] + m4.z * xcol[g*4+2] + m4.w * xcol[g*4+3];
    }
    if (use_sp) ob[(size_t)o * HW] = bf2f(spl[o * 264 + tid]) + acc;
    else        ob[(size_t)o * HW] += acc;
  }
}

extern "C" void kernel_launch(void* const* d_in, const int* in_sizes, int n_in,
                              void* d_out, int out_size, void* d_ws, size_t ws_size,
                              hipStream_t stream) {
  const float* x     = (const float*)d_in[0];
  const float* illu  = (const float*)d_in[1];
  const float* ln1w  = (const float*)d_in[2];
  const float* ln2w  = (const float*)d_in[3];
  const float* wqkv  = (const float*)d_in[4];
  const float* bqkv  = (const float*)d_in[5];
  const float* rpb   = (const float*)d_in[6];
  const float* wproj = (const float*)d_in[7];
  const float* bproj = (const float*)d_in[8];
  const float* temp  = (const float*)d_in[9];
  const float* w1    = (const float*)d_in[10];
  const float* wdw   = (const float*)d_in[11];
  const float* wout  = (const float*)d_in[12];
  float* out = (float*)d_out;

  char* ws = (char*)d_ws;
  unsigned short* vm = (unsigned short*)ws;            // 67,108,864 B
  float* Gp  = (float*)(ws + 67108864);                //  8,388,608 B
  float* Nqp = (float*)(ws + 75497472);                //    524,288 B
  float* Nkp = (float*)(ws + 76021760);                //    524,288 B
  float* G2  = (float*)(ws + 76546048);                //  1,048,576 B
  float* Nq2 = (float*)(ws + 77594624);                //     65,536 B
  float* Nk2 = (float*)(ws + 77660160);                //     65,536 B
  float* M   = (float*)(ws + 77725696);                //    131,072 B
  unsigned short* sp = (unsigned short*)(ws + SP_OFF); // 67,108,864 B (if available)
  int use_sp = (ws_size >= SP_OFF + 67108864ull) ? 1 : 0;

  k_fused<<<4096, 256, 0, stream>>>(x, illu, ln1w, ln2w, wqkv, bqkv, rpb, wproj, bproj,
                                    w1, wdw, out, sp, use_sp, vm, Gp, Nqp, Nkp);
  k_reduce1<<<256, 256, 0, stream>>>(Gp, Nqp, Nkp, G2, Nq2, Nk2);
  k_reduce2<<<8, 256, 0, stream>>>(G2, Nq2, Nk2, temp, wout, M);
  k_mdta_out<<<2048, 256, 0, stream>>>(vm, M, sp, use_sp, out);
}